// Round 3
// baseline (123.954 us; speedup 1.0000x reference)
//
#include <hip/hip_runtime.h>

typedef _Float16 f16x8 __attribute__((ext_vector_type(8)));
typedef float f32x4 __attribute__((ext_vector_type(4)));

#define B_  8
#define LQ  2048
#define LC  4096
#define DD  256

// async global->LDS, 16B per lane. LDS dest is wave-uniform base + lane*16.
__device__ __forceinline__ void gload_lds16(const void* g, void* l) {
    __builtin_amdgcn_global_load_lds(
        (const __attribute__((address_space(1))) unsigned int*)g,
        (__attribute__((address_space(3))) unsigned int*)l,
        16, 0, 0);
}

// Convert query only (context is consumed as f32 directly by gemm + out).
// Also zeroes `out` (out_kernel's atomicAdds run two kernels later).
__global__ __launch_bounds__(256)
void convert_q(const float* __restrict__ q, _Float16* __restrict__ qf,
               float* __restrict__ out) {
    if (blockIdx.x < 8) out[blockIdx.x * 256 + threadIdx.x] = 0.f;
    const int i = (blockIdx.x * 256 + threadIdx.x) * 8;   // 2048 blocks cover 8*2048*256
    const float4 a = *(const float4*)(q + i);
    const float4 c = *(const float4*)(q + i + 4);
    f16x8 o;
    o[0] = (_Float16)a.x; o[1] = (_Float16)a.y; o[2] = (_Float16)a.z; o[3] = (_Float16)a.w;
    o[4] = (_Float16)c.x; o[5] = (_Float16)c.y; o[6] = (_Float16)c.z; o[7] = (_Float16)c.w;
    *(f16x8*)(qf + i) = o;
}

// One block per (b, 128-ctx tile); bid&7 = b -> batch b's 32 blocks share one
// XCD's L2 (qf panel = 1 MB). 512 threads = 8 waves (2/SIMD), wave grid
// 2(ctx, wm) x 4(query, wn): per wave mi=4 x ni=2.
//
// Round-2 lesson: 72 tiny slots (16 KB, 16 MFMA/wave) with lockstep barriers
// cost ~850 cyc/slot of pure sync/latency (42 us vs 16.6 us LDS floor).
// Now: chunk = FULL-K query tile (128 q x 256 k f16 = 64 KB), double-buffered
// (2 x 64 KB LDS). 16 main iterations, 2 barriers each; 64 MFMA + 16
// ds_read_b128 per wave per iteration for the compiler to pipeline under
// fine lgkmcnt. Prefetch distance = 1 chunk (~2000 cyc >> L2 latency), so
// the counted vmcnt(8) is a near-no-op in steady state.
//
// Chunk row geometry (both A f32-halves and B f16 tiles): 128 rows x 512 B
// (32 x 16B groups). Staging: linear index L = p*512 + tid -> row = L>>5,
// g_store = L&31; fetch global group g_store ^ (row&7) (XOR swizzle). Reads
// at pos = G ^ (row&7): per 16-lane phase, 8 distinct positions x 2 rows =
// 2-way bank aliasing = free.
__global__ __launch_bounds__(512, 2)
void gemm_max_kernel(const _Float16* __restrict__ qf,
                     const float* __restrict__ ctx,
                     float* __restrict__ scores) {
    __shared__ __align__(16) _Float16 Buf[2][32768];   // 2 x 64 KB
    __shared__ float red[4][128];

    const int bid = blockIdx.x;
    const int b   = bid & 7;     // XCD affinity: batch b -> XCD b
    const int mt  = bid >> 3;    // ctx tile 0..31

    const int tid  = threadIdx.x;
    const int lane = tid & 63;
    const int wave = tid >> 6;   // 0..7
    const int wm   = wave >> 2;  // ctx half   (0..1) -> 64 rows each
    const int wn   = wave & 3;   // query slot (0..3) -> 32 cols each
    const int quad = lane >> 4;
    const int l15  = lane & 15;

    const float*    Ag = ctx + ((size_t)b * LC + (size_t)mt * 128) * DD;
    const _Float16* Bg = qf  + (size_t)b * LQ * DD;

    // staging map: pass p (0..7), row = p*16 + (tid>>5), g_store = tid&31.
    // row&7 == (tid>>5)&7 (p*16 = 0 mod 8), so g_glob is pass-invariant.
    const int srow32  = tid >> 5;        // 0..15
    const int g_store = tid & 31;
    const int g_glob  = g_store ^ (srow32 & 7);

    // B chunk c: query rows [c*128, +128), full K=256 f16 (512 B/row)
#define STAGE_B(c, bufi)                                                        \
    {                                                                           \
        const _Float16* _s = Bg + (size_t)(c) * 128 * DD;                       \
        _Pragma("unroll")                                                       \
        for (int p = 0; p < 8; ++p)                                             \
            gload_lds16(_s + (size_t)(p * 16 + srow32) * DD + g_glob * 8,       \
                        (char*)Buf[bufi] + p * 8192 + tid * 16);                \
    }

    // A chunk j (j=0,1): ctx rows [0,128) of this tile, k-half [j*128, +128) f32
#define STAGE_A(j, bufi)                                                        \
    {                                                                           \
        _Pragma("unroll")                                                       \
        for (int p = 0; p < 8; ++p)                                             \
            gload_lds16(Ag + (size_t)(p * 16 + srow32) * DD + (j) * 128 + g_glob * 4, \
                        (char*)Buf[bufi] + p * 8192 + tid * 16);                \
    }

    // counted-vmcnt barrier (rule 18: sched_barrier fences on both sides)
#define SYNCV(N)                                                                \
    {                                                                           \
        __builtin_amdgcn_sched_barrier(0);                                      \
        asm volatile("s_waitcnt vmcnt(" #N ")" ::: "memory");                   \
        __builtin_amdgcn_s_barrier();                                           \
        __builtin_amdgcn_sched_barrier(0);                                      \
    }

    f16x8 af[4][8];   // A fragments (rows wm*64..+64, all K), resident
    f32x4 acc[4][2];

    // fill af[*][j*4 .. j*4+3] from f32 A chunk j in Buf[bufi]
#define AF_FILL(j, bufi)                                                        \
    {                                                                           \
        _Pragma("unroll")                                                       \
        for (int mi = 0; mi < 4; ++mi) {                                        \
            const int row = wm * 64 + mi * 16 + l15;                            \
            _Pragma("unroll")                                                   \
            for (int ks = 0; ks < 4; ++ks) {                                    \
                const int gg = ks * 8 + quad * 2;                               \
                const int p0 = gg ^ (row & 7);                                  \
                const int p1 = (gg + 1) ^ (row & 7);                            \
                const f32x4 v0 = *(const f32x4*)((const char*)Buf[bufi] + row * 512 + p0 * 16); \
                const f32x4 v1 = *(const f32x4*)((const char*)Buf[bufi] + row * 512 + p1 * 16); \
                f16x8 o;                                                        \
                o[0] = (_Float16)v0[0]; o[1] = (_Float16)v0[1];                 \
                o[2] = (_Float16)v0[2]; o[3] = (_Float16)v0[3];                 \
                o[4] = (_Float16)v1[0]; o[5] = (_Float16)v1[1];                 \
                o[6] = (_Float16)v1[2]; o[7] = (_Float16)v1[3];                 \
                af[mi][(j) * 4 + ks] = o;                                       \
            }                                                                   \
        }                                                                       \
    }

    // one K=64 step (kc = 0..3) of the current B chunk
#define COMPUTE_B(kc, bufi)                                                     \
    {                                                                           \
        _Pragma("unroll")                                                       \
        for (int ksl = 0; ksl < 2; ++ksl) {                                     \
            f16x8 bfv[2];                                                       \
            _Pragma("unroll")                                                   \
            for (int ni = 0; ni < 2; ++ni) {                                    \
                const int row = wn * 32 + ni * 16 + l15;                        \
                const int G   = (kc) * 8 + ksl * 4 + quad;                      \
                const int pos = G ^ (row & 7);                                  \
                bfv[ni] = *(const f16x8*)((const char*)Buf[bufi] + row * 512 + pos * 16); \
            }                                                                   \
            __builtin_amdgcn_s_setprio(1);                                      \
            _Pragma("unroll")                                                   \
            for (int mi = 0; mi < 4; ++mi)                                      \
                _Pragma("unroll")                                               \
                for (int ni = 0; ni < 2; ++ni)                                  \
                    acc[mi][ni] = __builtin_amdgcn_mfma_f32_16x16x32_f16(       \
                        af[mi][(kc) * 2 + ksl], bfv[ni], acc[mi][ni], 0, 0, 0); \
            __builtin_amdgcn_s_setprio(0);                                      \
        }                                                                       \
    }

    float rm[4][4];
#pragma unroll
    for (int mi = 0; mi < 4; ++mi)
#pragma unroll
        for (int r = 0; r < 4; ++r) rm[mi][r] = -3.4e38f;

    // ---- prologue: A (2 x 64 KB f32) through both buffers, then B0 staged.
    // vmcnt ledger: each STAGE = 8 loads/thread.
    STAGE_A(0, 0);            // in flight: 8
    STAGE_A(1, 1);            // 16
    SYNCV(8);                 // A0 landed
    AF_FILL(0, 0);            // ksteps 0..3 (A1 still flying)
    __syncthreads();          // buf0 free
    STAGE_B(0, 0);            // in flight: A1(8) + B0(8) = 16
    SYNCV(8);                 // A1 landed
    AF_FILL(1, 1);            // ksteps 4..7
    __syncthreads();          // buf1 free

    // ---- main loop: 16 full-K query tiles, double-buffered
#pragma unroll 1
    for (int nt = 0; nt < 16; ++nt) {
        if (nt < 15) STAGE_B(nt + 1, (nt + 1) & 1);
        if (nt < 15) { SYNCV(8); }     // chunk nt landed; nt+1's 8 in flight
        else         { SYNCV(0); }     // drain last chunk
#pragma unroll
        for (int mi = 0; mi < 4; ++mi)
#pragma unroll
            for (int ni = 0; ni < 2; ++ni) acc[mi][ni] = (f32x4)0.0f;

        COMPUTE_B(0, nt & 1);
        COMPUTE_B(1, nt & 1);
        COMPUTE_B(2, nt & 1);
        COMPUTE_B(3, nt & 1);

#pragma unroll
        for (int mi = 0; mi < 4; ++mi)
#pragma unroll
            for (int r = 0; r < 4; ++r)
                rm[mi][r] = fmaxf(rm[mi][r],
                                  fmaxf(acc[mi][0][r], acc[mi][1][r]));

        if (nt < 15) __syncthreads();  // buf[nt&1] free for STAGE at nt+1
    }

    // ---- epilogue: reduce 16 col lanes, then the four wn slots
#pragma unroll
    for (int sh = 1; sh <= 8; sh <<= 1)
#pragma unroll
        for (int mi = 0; mi < 4; ++mi)
#pragma unroll
            for (int r = 0; r < 4; ++r)
                rm[mi][r] = fmaxf(rm[mi][r], __shfl_xor(rm[mi][r], sh, 64));

    if (l15 == 0) {
#pragma unroll
        for (int mi = 0; mi < 4; ++mi)
#pragma unroll
            for (int r = 0; r < 4; ++r)
                red[wn][wm * 64 + mi * 16 + quad * 4 + r] = rm[mi][r];
    }
    __syncthreads();
    if (tid < 128)
        scores[(size_t)b * LC + mt * 128 + tid] =
            fmaxf(fmaxf(red[0][tid], red[1][tid]),
                  fmaxf(red[2][tid], red[3][tid]));

#undef STAGE_A
#undef STAGE_B
#undef SYNCV
#undef AF_FILL
#undef COMPUTE_B
}

// Fused softmax-stats + weighted context sum. Each block recomputes M and the
// softmax denominator from the 4096 scores (16 KB, L2-hit, deterministic ->
// identical across blocks), then accumulates its 64-row chunk of
// out[b][d] = sum_c softmax(scores)[c] * ctx[b][c][d]   (ctx read as f32).
__global__ __launch_bounds__(256)
void out_kernel(const float* __restrict__ scores, const float* __restrict__ ctx,
                float* __restrict__ out) {
    const int ch   = blockIdx.x;   // 0..63
    const int b    = blockIdx.y;   // 0..7
    const int tid  = threadIdx.x;
    const int lane = tid & 63;
    const int wave = tid >> 6;
    __shared__ float smax[4];
    __shared__ float ssum[4];
    __shared__ float pl[64];

    const float* sb = scores + (size_t)b * LC;

    float sv[16];
    float lmax = -3.4e38f;
#pragma unroll
    for (int j = 0; j < 16; ++j) {
        sv[j] = sb[tid + j * 256];
        lmax  = fmaxf(lmax, sv[j]);
    }
    for (int sh = 1; sh < 64; sh <<= 1)
        lmax = fmaxf(lmax, __shfl_xor(lmax, sh, 64));
    if (lane == 0) smax[wave] = lmax;
    __syncthreads();
    const float M = fmaxf(fmaxf(smax[0], smax[1]), fmaxf(smax[2], smax[3]));

    float lsum = 0.f;
#pragma unroll
    for (int j = 0; j < 16; ++j)
        lsum += expf(sv[j] - M);
    for (int sh = 1; sh < 64; sh <<= 1)
        lsum += __shfl_xor(lsum, sh, 64);
    if (lane == 0) ssum[wave] = lsum;
    __syncthreads();
    const float inv = 1.f / (ssum[0] + ssum[1] + ssum[2] + ssum[3]);

    if (tid < 64) pl[tid] = expf(sb[ch * 64 + tid] - M) * inv;
    __syncthreads();

    const float* cb = ctx + ((size_t)b * LC + (size_t)ch * 64) * DD;
    float acc = 0.f;
#pragma unroll 8
    for (int i = 0; i < 64; ++i)
        acc += pl[i] * cb[(size_t)i * DD + tid];   // coalesced f32
    atomicAdd(&out[b * DD + tid], acc);
}

extern "C" void kernel_launch(void* const* d_in, const int* in_sizes, int n_in,
                              void* d_out, int out_size, void* d_ws, size_t ws_size,
                              hipStream_t stream) {
    const float* q   = (const float*)d_in[0];   // [8, 2048, 256] f32
    const float* ctx = (const float*)d_in[1];   // [8, 4096, 256] f32
    float* out = (float*)d_out;                 // [8, 1, 256] f32

    // ws layout (bytes):
    //   qf     @ 0        : 8*2048*256*2 = 8,388,608
    //   scores @ 8388608  : 8*4096*4     =   131,072
    char* ws = (char*)d_ws;
    _Float16* qf  = (_Float16*)(ws);
    float* scores = (float*)(ws + 8388608);

    convert_q<<<2048, 256, 0, stream>>>(q, qf, out);
    gemm_max_kernel<<<256, 512, 0, stream>>>(qf, ctx, scores);
    out_kernel<<<dim3(64, 8), 256, 0, stream>>>(scores, ctx, out);
}